// Round 1
// baseline (264.076 us; speedup 1.0000x reference)
//
#include <hip/hip_runtime.h>
#include <hip/hip_bf16.h>

#define B_ 32
#define F_ 64
#define N_ 512
#define T_ 64

typedef __attribute__((ext_vector_type(8))) short bf16x8;
typedef __attribute__((ext_vector_type(4))) float f32x4;

__device__ __forceinline__ unsigned short f2bf(float f) {
  union { float f; unsigned int u; } v; v.f = f;
  unsigned int u = v.u;
  unsigned int r = (u + 0x7FFFu + ((u >> 16) & 1u)) >> 16;
  return (unsigned short)r;
}

// Pass 1 over x: t1[b,f,t] = sum_n x[b,f,n,t]*U1[n]  (atomic partials over n-chunks)
//                rhs[b,n,t] = sum_f U3[f]*x[b,f,n,t] (exact, LDS cross-wave reduce)
__global__ __launch_bounds__(256) void k1_reduce(const float* __restrict__ x,
    const float* __restrict__ U1, const float* __restrict__ U3,
    float* __restrict__ t1, float* __restrict__ rhs) {
  const int b = blockIdx.x;
  const int n0 = blockIdx.y * 16;
  const int tid = threadIdx.x;
  const int t = tid & 63;
  const int wv = tid >> 6;  // wave handles f in [wv*16, wv*16+16)

  __shared__ float lds[4 * 16 * 64];

  const float* xb = x + (size_t)b * (F_ * (size_t)N_ * T_);

  float u1c[16];
#pragma unroll
  for (int i = 0; i < 16; ++i) u1c[i] = U1[n0 + i];

  float racc[16];
#pragma unroll
  for (int i = 0; i < 16; ++i) racc[i] = 0.f;
  float pt1[16];

#pragma unroll
  for (int j = 0; j < 16; ++j) {
    const int f = wv * 16 + j;
    const float u3 = U3[f];
    const float* xf = xb + (size_t)f * (N_ * T_) + (size_t)n0 * T_ + t;
    float s1 = 0.f;
#pragma unroll
    for (int i = 0; i < 16; ++i) {
      const float v = xf[i * T_];
      racc[i] += u3 * v;
      s1 += u1c[i] * v;
    }
    pt1[j] = s1;
  }

#pragma unroll
  for (int j = 0; j < 16; ++j) {
    const int f = wv * 16 + j;
    atomicAdd(&t1[((size_t)b * F_ + f) * T_ + t], pt1[j]);
  }

#pragma unroll
  for (int i = 0; i < 16; ++i) lds[wv * 1024 + i * 64 + t] = racc[i];
  __syncthreads();
#pragma unroll
  for (int q = 0; q < 4; ++q) {
    const int idx = q * 256 + tid;  // i*64 + t
    const float s = lds[idx] + lds[1024 + idx] + lds[2048 + idx] + lds[3072 + idx];
    const int i = idx >> 6, tt = idx & 63;
    rhs[((size_t)b * N_ + n0 + i) * T_ + tt] = s;
  }
}

// w[b,f,s] = sum_n U2[n,f] * rhs[b,n,s]  (atomic partials over 64-n chunks)
__global__ __launch_bounds__(256) void k2_w(const float* __restrict__ rhs,
    const float* __restrict__ U2, float* __restrict__ wbuf) {
  const int b = blockIdx.x;
  const int n0 = blockIdx.y * 64;
  const int tid = threadIdx.x;
  const int s = tid & 63;
  const int fg = tid >> 6;
  __shared__ float lu2[64 * 64];
  __shared__ float lr[64 * 64];
#pragma unroll
  for (int q = 0; q < 16; ++q) {
    const int idx = q * 256 + tid;
    const int i = idx >> 6, c = idx & 63;
    lu2[idx] = U2[(size_t)(n0 + i) * F_ + c];
    lr[idx] = rhs[((size_t)b * N_ + n0 + i) * T_ + c];
  }
  __syncthreads();
  float acc[16];
#pragma unroll
  for (int j = 0; j < 16; ++j) acc[j] = 0.f;
  for (int i = 0; i < 64; ++i) {
    const float rv = lr[i * 64 + s];
#pragma unroll
    for (int j = 0; j < 16; ++j) acc[j] += lu2[i * 64 + fg * 16 + j] * rv;
  }
#pragma unroll
  for (int j = 0; j < 16; ++j)
    atomicAdd(&wbuf[((size_t)b * F_ + fg * 16 + j) * T_ + s], acc[j]);
}

// Per-batch: product = t1^T w; S = sigmoid(product+be); E = Ve*S; A = softmax_t(E)
__global__ __launch_bounds__(256) void k3_attn(const float* __restrict__ t1,
    const float* __restrict__ wbuf, const float* __restrict__ be,
    const float* __restrict__ Ve, float* __restrict__ Amat) {
  const int b = blockIdx.x;
  const int tid = threadIdx.x;
  const int lane = tid & 63;
  const int tg = tid >> 6;
  __shared__ float bufA[64 * 65];
  __shared__ float bufB[64 * 65];
  __shared__ float red[2][4][64];
#pragma unroll
  for (int q = 0; q < 16; ++q) {
    const int idx = q * 256 + tid;
    const int r = idx >> 6, c = idx & 63;
    bufA[r * 65 + c] = t1[(size_t)b * 4096 + idx];   // [f][t]
    bufB[r * 65 + c] = wbuf[(size_t)b * 4096 + idx]; // [f][s]
  }
  __syncthreads();
  // product[t][s], thread owns s=lane, t = tg*16+j
  float prod[16];
#pragma unroll
  for (int j = 0; j < 16; ++j) prod[j] = 0.f;
  for (int f = 0; f < 64; ++f) {
    const float wv = bufB[f * 65 + lane];
#pragma unroll
    for (int j = 0; j < 16; ++j) prod[j] += bufA[f * 65 + tg * 16 + j] * wv;
  }
  __syncthreads();
  // S = sigmoid(product + be) into bufA[t][s]; Ve into bufB
#pragma unroll
  for (int j = 0; j < 16; ++j) {
    const int tt = tg * 16 + j;
    const float v = prod[j] + be[tt * 64 + lane];
    bufA[tt * 65 + lane] = 1.f / (1.f + __expf(-v));
  }
#pragma unroll
  for (int q = 0; q < 16; ++q) {
    const int idx = q * 256 + tid;
    bufB[(idx >> 6) * 65 + (idx & 63)] = Ve[idx];
  }
  __syncthreads();
  // E[t][u] = sum_s Ve[t][s]*S[s][u], thread owns u=lane, t=tg*16+j
  float E[16];
#pragma unroll
  for (int j = 0; j < 16; ++j) E[j] = 0.f;
  for (int s = 0; s < 64; ++s) {
    const float sv = bufA[s * 65 + lane];
#pragma unroll
    for (int j = 0; j < 16; ++j) E[j] += bufB[(tg * 16 + j) * 65 + s] * sv;
  }
  // softmax over t (fixed u=lane)
  float m = E[0];
#pragma unroll
  for (int j = 1; j < 16; ++j) m = fmaxf(m, E[j]);
  red[0][tg][lane] = m;
  __syncthreads();
  m = fmaxf(fmaxf(red[0][0][lane], red[0][1][lane]),
            fmaxf(red[0][2][lane], red[0][3][lane]));
  float se = 0.f;
  float ex[16];
#pragma unroll
  for (int j = 0; j < 16; ++j) { ex[j] = __expf(E[j] - m); se += ex[j]; }
  red[1][tg][lane] = se;
  __syncthreads();
  const float gs = red[1][0][lane] + red[1][1][lane] + red[1][2][lane] + red[1][3][lane];
  const float inv = 1.f / gs;
#pragma unroll
  for (int j = 0; j < 16; ++j) {
    const int tt = tg * 16 + j;
    Amat[(size_t)b * 4096 + tt * 64 + lane] = ex[j] * inv;
  }
}

// out[b,fn,s] = sum_t x[b,fn,t] * A[b,t,s] via bf16 MFMA. Wave = 16 rows x 64 cols.
__global__ __launch_bounds__(256) void k4_out(const float* __restrict__ x,
    const float* __restrict__ Amat, float* __restrict__ out) {
  const int b = blockIdx.x;
  const int chunk = blockIdx.y;
  const int tid = threadIdx.x;
  const int wv = tid >> 6;
  const int l = tid & 63;
  __shared__ float lA[64 * 65];
  const float* Ab = Amat + (size_t)b * 4096;
#pragma unroll
  for (int q = 0; q < 16; ++q) {
    const int idx = q * 256 + tid;
    lA[(idx >> 6) * 65 + (idx & 63)] = Ab[idx];
  }
  __syncthreads();

  // B-operand frags: lane l holds B[k=(l>>4)*8+j][col=l&15], k-halves of 32
  const int krow0 = (l >> 4) * 8;
  const int colb = l & 15;
  bf16x8 Bf[4][2];
#pragma unroll
  for (int nt = 0; nt < 4; ++nt)
#pragma unroll
    for (int kh = 0; kh < 2; ++kh) {
      bf16x8 fr;
#pragma unroll
      for (int j = 0; j < 8; ++j) {
        const int k = kh * 32 + krow0 + j;
        fr[j] = (short)f2bf(lA[k * 65 + nt * 16 + colb]);
      }
      Bf[nt][kh] = fr;
    }

  const float* Xb = x + (size_t)b * (F_ * (size_t)N_ * T_);
  float* Ob = out + (size_t)b * (F_ * (size_t)N_ * T_);
  const int rl = l & 15;
  const int c0 = (l >> 4) * 8;

  for (int it = 0; it < 4; ++it) {
    const int tile = chunk * 16 + wv * 4 + it;  // 0..2047
    const int r = tile * 16 + rl;
    const float* xr = Xb + (size_t)r * T_;
    const float4 v0 = *(const float4*)(xr + c0);
    const float4 v1 = *(const float4*)(xr + c0 + 4);
    const float4 v2 = *(const float4*)(xr + 32 + c0);
    const float4 v3 = *(const float4*)(xr + 32 + c0 + 4);
    bf16x8 a0, a1;
    a0[0] = (short)f2bf(v0.x); a0[1] = (short)f2bf(v0.y);
    a0[2] = (short)f2bf(v0.z); a0[3] = (short)f2bf(v0.w);
    a0[4] = (short)f2bf(v1.x); a0[5] = (short)f2bf(v1.y);
    a0[6] = (short)f2bf(v1.z); a0[7] = (short)f2bf(v1.w);
    a1[0] = (short)f2bf(v2.x); a1[1] = (short)f2bf(v2.y);
    a1[2] = (short)f2bf(v2.z); a1[3] = (short)f2bf(v2.w);
    a1[4] = (short)f2bf(v3.x); a1[5] = (short)f2bf(v3.y);
    a1[6] = (short)f2bf(v3.z); a1[7] = (short)f2bf(v3.w);

    const int rowb = tile * 16 + (l >> 4) * 4;
#pragma unroll
    for (int nt = 0; nt < 4; ++nt) {
      f32x4 c = {0.f, 0.f, 0.f, 0.f};
      c = __builtin_amdgcn_mfma_f32_16x16x32_bf16(a0, Bf[nt][0], c, 0, 0, 0);
      c = __builtin_amdgcn_mfma_f32_16x16x32_bf16(a1, Bf[nt][1], c, 0, 0, 0);
#pragma unroll
      for (int j = 0; j < 4; ++j)
        Ob[(size_t)(rowb + j) * T_ + nt * 16 + colb] = c[j];
    }
  }
}

extern "C" void kernel_launch(void* const* d_in, const int* in_sizes, int n_in,
                              void* d_out, int out_size, void* d_ws, size_t ws_size,
                              hipStream_t stream) {
  const float* x  = (const float*)d_in[0];
  const float* U1 = (const float*)d_in[1];
  const float* U2 = (const float*)d_in[2];
  const float* U3 = (const float*)d_in[3];
  const float* be = (const float*)d_in[4];
  const float* Ve = (const float*)d_in[5];
  float* out = (float*)d_out;
  float* ws = (float*)d_ws;

  float* t1   = ws;                 // B*F*T   = 131072 floats
  float* rhs  = t1 + 131072;        // B*N*T   = 1048576 floats
  float* wbf  = rhs + 1048576;      // B*F*T   = 131072 floats
  float* Amat = wbf + 131072;       // B*T*T   = 131072 floats
  // total ~5.8 MB of d_ws

  hipMemsetAsync(t1, 0, 131072 * sizeof(float), stream);
  hipMemsetAsync(wbf, 0, 131072 * sizeof(float), stream);

  k1_reduce<<<dim3(32, 32), 256, 0, stream>>>(x, U1, U3, t1, rhs);
  k2_w<<<dim3(32, 8), 256, 0, stream>>>(rhs, U2, wbf);
  k3_attn<<<32, 256, 0, stream>>>(t1, wbf, be, Ve, Amat);
  k4_out<<<dim3(32, 128), 256, 0, stream>>>(x, Amat, out);
}

// Round 2
// 198.729 us; speedup vs baseline: 1.3288x; 1.3288x over previous
//
#include <hip/hip_runtime.h>
#include <hip/hip_bf16.h>

#define B_ 32
#define F_ 64
#define N_ 512
#define T_ 64

typedef __attribute__((ext_vector_type(8))) short bf16x8;
typedef __attribute__((ext_vector_type(4))) float f32x4;

__device__ __forceinline__ unsigned short f2bf(float f) {
  union { float f; unsigned int u; } v; v.f = f;
  unsigned int u = v.u;
  unsigned int r = (u + 0x7FFFu + ((u >> 16) & 1u)) >> 16;
  return (unsigned short)r;
}

// Pass 1 over x (one block = one (b, 16-n chunk), all 64 f):
//   rhs[b,n,t]       = sum_f U3[f]*x[b,f,n,t]   (exact: LDS cross-wave reduce)
//   t1part[b,nc,f,t] = sum_{n in chunk} U1[n]*x[b,f,n,t]  (shuffle-reduced, stored as partial)
// Thread layout: wave w owns f in [w*16, w*16+16); lane: n_sub=lane>>4 (4 n's of 4), t0=(lane&15)*4.
__global__ __launch_bounds__(256) void k1_reduce(const float* __restrict__ x,
    const float* __restrict__ U1, const float* __restrict__ U3,
    float* __restrict__ t1part, float* __restrict__ rhs) {
  const int b = blockIdx.x;
  const int nc = blockIdx.y;
  const int n0 = nc * 16;
  const int tid = threadIdx.x;
  const int w = tid >> 6;
  const int lane = tid & 63;
  const int n_sub = lane >> 4;
  const int t0 = (lane & 15) * 4;

  __shared__ float lds[4096];

  const float* xb = x + (size_t)b * (F_ * (size_t)N_ * T_);

  float u1c[4];
#pragma unroll
  for (int i = 0; i < 4; ++i) u1c[i] = U1[n0 + n_sub * 4 + i];

  float racc[4][4];
#pragma unroll
  for (int i = 0; i < 4; ++i)
#pragma unroll
    for (int k = 0; k < 4; ++k) racc[i][k] = 0.f;

#pragma unroll
  for (int j = 0; j < 16; ++j) {
    const int f = w * 16 + j;
    const float u3 = U3[f];
    const float* xf = xb + (size_t)f * (N_ * T_) + (size_t)(n0 + n_sub * 4) * T_ + t0;
    float p0 = 0.f, p1 = 0.f, p2 = 0.f, p3 = 0.f;
#pragma unroll
    for (int i = 0; i < 4; ++i) {
      const float4 v = *(const float4*)(xf + i * T_);
      racc[i][0] += u3 * v.x; racc[i][1] += u3 * v.y;
      racc[i][2] += u3 * v.z; racc[i][3] += u3 * v.w;
      p0 += u1c[i] * v.x; p1 += u1c[i] * v.y;
      p2 += u1c[i] * v.z; p3 += u1c[i] * v.w;
    }
    // butterfly over the 4 n-subgroups (lane bits 4-5)
    p0 += __shfl_xor(p0, 16); p0 += __shfl_xor(p0, 32);
    p1 += __shfl_xor(p1, 16); p1 += __shfl_xor(p1, 32);
    p2 += __shfl_xor(p2, 16); p2 += __shfl_xor(p2, 32);
    p3 += __shfl_xor(p3, 16); p3 += __shfl_xor(p3, 32);
    if (lane < 16) {
      float4 st; st.x = p0; st.y = p1; st.z = p2; st.w = p3;
      *(float4*)&t1part[((size_t)(b * 32 + nc) * 64 + f) * 64 + t0] = st;
    }
  }

  // cross-wave reduce for rhs: lds[w][n_local(16)][t(64)]
#pragma unroll
  for (int i = 0; i < 4; ++i) {
    float4 st; st.x = racc[i][0]; st.y = racc[i][1]; st.z = racc[i][2]; st.w = racc[i][3];
    *(float4*)&lds[w * 1024 + (n_sub * 4 + i) * 64 + t0] = st;
  }
  __syncthreads();
#pragma unroll
  for (int q = 0; q < 4; ++q) {
    const int idx = q * 256 + tid;  // n_local*64 + t, 0..1023
    const float s = lds[idx] + lds[1024 + idx] + lds[2048 + idx] + lds[3072 + idx];
    rhs[((size_t)b * N_ + n0 + (idx >> 6)) * T_ + (idx & 63)] = s;
  }
}

// wpart[b,c,f,s] = sum_{n in 64-chunk c} U2[n,f] * rhs[b,n,s]
__global__ __launch_bounds__(256) void k2_w(const float* __restrict__ rhs,
    const float* __restrict__ U2, float* __restrict__ wpart) {
  const int b = blockIdx.x;
  const int c = blockIdx.y;
  const int n0 = c * 64;
  const int tid = threadIdx.x;
  const int s = tid & 63;
  const int fg = tid >> 6;
  __shared__ float lu2[64 * 64];
  __shared__ float lr[64 * 64];
#pragma unroll
  for (int q = 0; q < 16; ++q) {
    const int idx = q * 256 + tid;
    const int i = idx >> 6, cc = idx & 63;
    lu2[idx] = U2[(size_t)(n0 + i) * F_ + cc];
    lr[idx] = rhs[((size_t)b * N_ + n0 + i) * T_ + cc];
  }
  __syncthreads();
  float acc[16];
#pragma unroll
  for (int j = 0; j < 16; ++j) acc[j] = 0.f;
  for (int i = 0; i < 64; ++i) {
    const float rv = lr[i * 64 + s];
#pragma unroll
    for (int j = 0; j < 16; ++j) acc[j] += lu2[i * 64 + fg * 16 + j] * rv;
  }
#pragma unroll
  for (int j = 0; j < 16; ++j)
    wpart[(size_t)(b * 8 + c) * 4096 + (size_t)(fg * 16 + j) * 64 + s] = acc[j];
}

// Collapse partials: t1[b,f,t] = sum_c t1part ; wbf[b,f,s] = sum_c wpart
__global__ __launch_bounds__(256) void kred(const float* __restrict__ t1part,
    const float* __restrict__ wpart, float* __restrict__ t1, float* __restrict__ wbf) {
  const int gid = blockIdx.x * 256 + threadIdx.x;
  if (gid < 131072) {
    const int b = gid >> 12, idx = gid & 4095;
    const float* p = t1part + (size_t)b * 32 * 4096 + idx;
    float sum = 0.f;
#pragma unroll
    for (int c = 0; c < 32; ++c) sum += p[c * 4096];
    t1[gid] = sum;
  } else {
    const int g = gid - 131072;
    const int b = g >> 12, idx = g & 4095;
    const float* p = wpart + (size_t)b * 8 * 4096 + idx;
    float sum = 0.f;
#pragma unroll
    for (int c = 0; c < 8; ++c) sum += p[c * 4096];
    wbf[g] = sum;
  }
}

// Per-batch: product = t1^T w; S = sigmoid(product+be); E = Ve*S; A = softmax_t(E)
__global__ __launch_bounds__(256) void k3_attn(const float* __restrict__ t1,
    const float* __restrict__ wbuf, const float* __restrict__ be,
    const float* __restrict__ Ve, float* __restrict__ Amat) {
  const int b = blockIdx.x;
  const int tid = threadIdx.x;
  const int lane = tid & 63;
  const int tg = tid >> 6;
  __shared__ float bufA[64 * 65];
  __shared__ float bufB[64 * 65];
  __shared__ float red[2][4][64];
#pragma unroll
  for (int q = 0; q < 16; ++q) {
    const int idx = q * 256 + tid;
    const int r = idx >> 6, c = idx & 63;
    bufA[r * 65 + c] = t1[(size_t)b * 4096 + idx];   // [f][t]
    bufB[r * 65 + c] = wbuf[(size_t)b * 4096 + idx]; // [f][s]
  }
  __syncthreads();
  float prod[16];
#pragma unroll
  for (int j = 0; j < 16; ++j) prod[j] = 0.f;
  for (int f = 0; f < 64; ++f) {
    const float wv = bufB[f * 65 + lane];
#pragma unroll
    for (int j = 0; j < 16; ++j) prod[j] += bufA[f * 65 + tg * 16 + j] * wv;
  }
  __syncthreads();
#pragma unroll
  for (int j = 0; j < 16; ++j) {
    const int tt = tg * 16 + j;
    const float v = prod[j] + be[tt * 64 + lane];
    bufA[tt * 65 + lane] = 1.f / (1.f + __expf(-v));
  }
#pragma unroll
  for (int q = 0; q < 16; ++q) {
    const int idx = q * 256 + tid;
    bufB[(idx >> 6) * 65 + (idx & 63)] = Ve[idx];
  }
  __syncthreads();
  float E[16];
#pragma unroll
  for (int j = 0; j < 16; ++j) E[j] = 0.f;
  for (int s = 0; s < 64; ++s) {
    const float sv = bufA[s * 65 + lane];
#pragma unroll
    for (int j = 0; j < 16; ++j) E[j] += bufB[(tg * 16 + j) * 65 + s] * sv;
  }
  float m = E[0];
#pragma unroll
  for (int j = 1; j < 16; ++j) m = fmaxf(m, E[j]);
  red[0][tg][lane] = m;
  __syncthreads();
  m = fmaxf(fmaxf(red[0][0][lane], red[0][1][lane]),
            fmaxf(red[0][2][lane], red[0][3][lane]));
  float se = 0.f;
  float ex[16];
#pragma unroll
  for (int j = 0; j < 16; ++j) { ex[j] = __expf(E[j] - m); se += ex[j]; }
  red[1][tg][lane] = se;
  __syncthreads();
  const float gs = red[1][0][lane] + red[1][1][lane] + red[1][2][lane] + red[1][3][lane];
  const float inv = 1.f / gs;
#pragma unroll
  for (int j = 0; j < 16; ++j) {
    const int tt = tg * 16 + j;
    Amat[(size_t)b * 4096 + tt * 64 + lane] = ex[j] * inv;
  }
}

// out[b,fn,s] = sum_t x[b,fn,t] * A[b,t,s] via bf16 MFMA. Wave = 16 rows x 64 cols.
__global__ __launch_bounds__(256) void k4_out(const float* __restrict__ x,
    const float* __restrict__ Amat, float* __restrict__ out) {
  const int b = blockIdx.x;
  const int chunk = blockIdx.y;
  const int tid = threadIdx.x;
  const int wv = tid >> 6;
  const int l = tid & 63;
  __shared__ float lA[64 * 65];
  const float* Ab = Amat + (size_t)b * 4096;
#pragma unroll
  for (int q = 0; q < 16; ++q) {
    const int idx = q * 256 + tid;
    lA[(idx >> 6) * 65 + (idx & 63)] = Ab[idx];
  }
  __syncthreads();

  const int krow0 = (l >> 4) * 8;
  const int colb = l & 15;
  bf16x8 Bf[4][2];
#pragma unroll
  for (int nt = 0; nt < 4; ++nt)
#pragma unroll
    for (int kh = 0; kh < 2; ++kh) {
      bf16x8 fr;
#pragma unroll
      for (int j = 0; j < 8; ++j) {
        const int k = kh * 32 + krow0 + j;
        fr[j] = (short)f2bf(lA[k * 65 + nt * 16 + colb]);
      }
      Bf[nt][kh] = fr;
    }

  const float* Xb = x + (size_t)b * (F_ * (size_t)N_ * T_);
  float* Ob = out + (size_t)b * (F_ * (size_t)N_ * T_);
  const int rl = l & 15;
  const int c0 = (l >> 4) * 8;

  for (int it = 0; it < 4; ++it) {
    const int tile = chunk * 16 + wv * 4 + it;  // 0..2047
    const int r = tile * 16 + rl;
    const float* xr = Xb + (size_t)r * T_;
    const float4 v0 = *(const float4*)(xr + c0);
    const float4 v1 = *(const float4*)(xr + c0 + 4);
    const float4 v2 = *(const float4*)(xr + 32 + c0);
    const float4 v3 = *(const float4*)(xr + 32 + c0 + 4);
    bf16x8 a0, a1;
    a0[0] = (short)f2bf(v0.x); a0[1] = (short)f2bf(v0.y);
    a0[2] = (short)f2bf(v0.z); a0[3] = (short)f2bf(v0.w);
    a0[4] = (short)f2bf(v1.x); a0[5] = (short)f2bf(v1.y);
    a0[6] = (short)f2bf(v1.z); a0[7] = (short)f2bf(v1.w);
    a1[0] = (short)f2bf(v2.x); a1[1] = (short)f2bf(v2.y);
    a1[2] = (short)f2bf(v2.z); a1[3] = (short)f2bf(v2.w);
    a1[4] = (short)f2bf(v3.x); a1[5] = (short)f2bf(v3.y);
    a1[6] = (short)f2bf(v3.z); a1[7] = (short)f2bf(v3.w);

    const int rowb = tile * 16 + (l >> 4) * 4;
#pragma unroll
    for (int nt = 0; nt < 4; ++nt) {
      f32x4 c = {0.f, 0.f, 0.f, 0.f};
      c = __builtin_amdgcn_mfma_f32_16x16x32_bf16(a0, Bf[nt][0], c, 0, 0, 0);
      c = __builtin_amdgcn_mfma_f32_16x16x32_bf16(a1, Bf[nt][1], c, 0, 0, 0);
#pragma unroll
      for (int j = 0; j < 4; ++j)
        Ob[(size_t)(rowb + j) * T_ + nt * 16 + colb] = c[j];
    }
  }
}

extern "C" void kernel_launch(void* const* d_in, const int* in_sizes, int n_in,
                              void* d_out, int out_size, void* d_ws, size_t ws_size,
                              hipStream_t stream) {
  const float* x  = (const float*)d_in[0];
  const float* U1 = (const float*)d_in[1];
  const float* U2 = (const float*)d_in[2];
  const float* U3 = (const float*)d_in[3];
  const float* be = (const float*)d_in[4];
  const float* Ve = (const float*)d_in[5];
  float* out = (float*)d_out;
  float* ws = (float*)d_ws;

  float* t1part = ws;                    // 32*32*4096 = 4,194,304 floats (16 MB)
  float* rhs    = t1part + 4194304;      // 32*512*64  = 1,048,576 floats (4 MB)
  float* wpart  = rhs + 1048576;         // 32*8*4096  = 1,048,576 floats (4 MB)
  float* t1     = wpart + 1048576;       // 131072 floats
  float* wbf    = t1 + 131072;           // 131072 floats
  float* Amat   = wbf + 131072;          // 131072 floats
  // total ~25.7 MB of d_ws

  k1_reduce<<<dim3(32, 32), 256, 0, stream>>>(x, U1, U3, t1part, rhs);
  k2_w<<<dim3(32, 8), 256, 0, stream>>>(rhs, U2, wpart);
  kred<<<1024, 256, 0, stream>>>(t1part, wpart, t1, wbf);
  k3_attn<<<32, 256, 0, stream>>>(t1, wbf, be, Ve, Amat);
  k4_out<<<dim3(32, 128), 256, 0, stream>>>(x, Amat, out);
}

// Round 3
// 192.914 us; speedup vs baseline: 1.3689x; 1.0301x over previous
//
#include <hip/hip_runtime.h>
#include <hip/hip_bf16.h>

#define B_ 32
#define F_ 64
#define N_ 512
#define T_ 64

typedef __attribute__((ext_vector_type(8))) short bf16x8;
typedef __attribute__((ext_vector_type(4))) float f32x4;

__device__ __forceinline__ unsigned short f2bf(float f) {
  union { float f; unsigned int u; } v; v.f = f;
  unsigned int u = v.u;
  unsigned int r = (u + 0x7FFFu + ((u >> 16) & 1u)) >> 16;
  return (unsigned short)r;
}

__device__ __forceinline__ void gl_lds16(const float* g, float* l) {
  __builtin_amdgcn_global_load_lds(
      (const __attribute__((address_space(1))) unsigned int*)(g),
      (__attribute__((address_space(3))) unsigned int*)(l),
      16, 0, 0);
}

// Pass 1 over x. Block=(b, 16-n chunk). Wave w owns f in [w*16, w*16+16).
// Per f: a 4KB contiguous slab x[b,f,n0..n0+15,:] staged to a wave-private
// double-buffered LDS ring via global_load_lds; counted vmcnt (never 0 in loop).
//   rhs[b,n,t]       = sum_f U3[f]*x[b,f,n,t]     (cross-wave LDS reduce at end)
//   t1part[b,nc,f,t] = sum_{n in chunk} U1[n]*x   (shuffle-reduced, partial)
__global__ __launch_bounds__(256) void k1_reduce(const float* __restrict__ x,
    const float* __restrict__ U1, const float* __restrict__ U3,
    float* __restrict__ t1part, float* __restrict__ rhs) {
  const int b = blockIdx.x;
  const int nc = blockIdx.y;
  const int n0 = nc * 16;
  const int tid = threadIdx.x;
  const int w = tid >> 6;
  const int lane = tid & 63;
  const int n_sub = lane >> 4;
  const int t0 = (lane & 15) * 4;

  __shared__ float ring[4][2][1024];  // [wave][buf][16n*64t] = 32 KB

  // slab base for wave w, f-index j: x + ((b*64 + w*16 + j)*512 + n0)*64
  const float* fbase = x + ((size_t)(b * F_ + w * 16) * N_ + n0) * T_;

  float u1c[4];
#pragma unroll
  for (int i = 0; i < 4; ++i) u1c[i] = U1[n0 + n_sub * 4 + i];

  float racc[4][4];
#pragma unroll
  for (int i = 0; i < 4; ++i)
#pragma unroll
    for (int k = 0; k < 4; ++k) racc[i][k] = 0.f;

  // prologue: stage slab 0 into buf 0
  {
    const float* s = fbase;
    float* l = &ring[w][0][0];
#pragma unroll
    for (int c = 0; c < 4; ++c) gl_lds16(s + c * 256 + lane * 4, l + c * 256);
  }

#pragma unroll 2
  for (int j = 0; j < 16; ++j) {
    const int buf = j & 1;
    if (j < 15) {  // stage next slab into the other buffer
      const float* s = fbase + (size_t)(j + 1) * (N_ * T_);
      float* l = &ring[w][buf ^ 1][0];
#pragma unroll
      for (int c = 0; c < 4; ++c) gl_lds16(s + c * 256 + lane * 4, l + c * 256);
      asm volatile("s_waitcnt vmcnt(4)" ::: "memory");
    } else {
      asm volatile("s_waitcnt vmcnt(0)" ::: "memory");
    }
    __builtin_amdgcn_sched_barrier(0);

    const int f = w * 16 + j;
    const float u3 = U3[f];
    float p0 = 0.f, p1 = 0.f, p2 = 0.f, p3 = 0.f;
#pragma unroll
    for (int i = 0; i < 4; ++i) {
      const float4 v = *(const float4*)&ring[w][buf][(n_sub * 4 + i) * 64 + t0];
      racc[i][0] += u3 * v.x; racc[i][1] += u3 * v.y;
      racc[i][2] += u3 * v.z; racc[i][3] += u3 * v.w;
      p0 += u1c[i] * v.x; p1 += u1c[i] * v.y;
      p2 += u1c[i] * v.z; p3 += u1c[i] * v.w;
    }
    // butterfly over the 4 n-subgroups (lane bits 4-5)
    p0 += __shfl_xor(p0, 16); p0 += __shfl_xor(p0, 32);
    p1 += __shfl_xor(p1, 16); p1 += __shfl_xor(p1, 32);
    p2 += __shfl_xor(p2, 16); p2 += __shfl_xor(p2, 32);
    p3 += __shfl_xor(p3, 16); p3 += __shfl_xor(p3, 32);
    if (lane < 16) {
      float4 st; st.x = p0; st.y = p1; st.z = p2; st.w = p3;
      *(float4*)&t1part[((size_t)(b * 32 + nc) * 64 + f) * 64 + t0] = st;
    }
  }

  // cross-wave reduce for rhs: dump racc into wave-private ring[w][0]
#pragma unroll
  for (int i = 0; i < 4; ++i) {
    float4 st; st.x = racc[i][0]; st.y = racc[i][1]; st.z = racc[i][2]; st.w = racc[i][3];
    *(float4*)&ring[w][0][(n_sub * 4 + i) * 64 + t0] = st;
  }
  __syncthreads();
#pragma unroll
  for (int q = 0; q < 4; ++q) {
    const int idx = q * 256 + tid;  // n_local*64 + t
    const float s = ring[0][0][idx] + ring[1][0][idx] + ring[2][0][idx] + ring[3][0][idx];
    rhs[((size_t)b * N_ + n0 + (idx >> 6)) * T_ + (idx & 63)] = s;
  }
}

// wpart[b,c,f,s] = sum_{n in 64-chunk c} U2[n,f] * rhs[b,n,s]
__global__ __launch_bounds__(256) void k2_w(const float* __restrict__ rhs,
    const float* __restrict__ U2, float* __restrict__ wpart) {
  const int b = blockIdx.x;
  const int c = blockIdx.y;
  const int n0 = c * 64;
  const int tid = threadIdx.x;
  const int s = tid & 63;
  const int fg = tid >> 6;
  __shared__ float lu2[64 * 64];
  __shared__ float lr[64 * 64];
#pragma unroll
  for (int q = 0; q < 16; ++q) {
    const int idx = q * 256 + tid;
    const int i = idx >> 6, cc = idx & 63;
    lu2[idx] = U2[(size_t)(n0 + i) * F_ + cc];
    lr[idx] = rhs[((size_t)b * N_ + n0 + i) * T_ + cc];
  }
  __syncthreads();
  float acc[16];
#pragma unroll
  for (int j = 0; j < 16; ++j) acc[j] = 0.f;
  for (int i = 0; i < 64; ++i) {
    const float rv = lr[i * 64 + s];
#pragma unroll
    for (int j = 0; j < 16; ++j) acc[j] += lu2[i * 64 + fg * 16 + j] * rv;
  }
#pragma unroll
  for (int j = 0; j < 16; ++j)
    wpart[(size_t)(b * 8 + c) * 4096 + (size_t)(fg * 16 + j) * 64 + s] = acc[j];
}

// Collapse partials: t1[b,f,t] = sum_c t1part ; wbf[b,f,s] = sum_c wpart
__global__ __launch_bounds__(256) void kred(const float* __restrict__ t1part,
    const float* __restrict__ wpart, float* __restrict__ t1, float* __restrict__ wbf) {
  const int gid = blockIdx.x * 256 + threadIdx.x;
  if (gid < 131072) {
    const int b = gid >> 12, idx = gid & 4095;
    const float* p = t1part + (size_t)b * 32 * 4096 + idx;
    float sum = 0.f;
#pragma unroll
    for (int c = 0; c < 32; ++c) sum += p[c * 4096];
    t1[gid] = sum;
  } else {
    const int g = gid - 131072;
    const int b = g >> 12, idx = g & 4095;
    const float* p = wpart + (size_t)b * 8 * 4096 + idx;
    float sum = 0.f;
#pragma unroll
    for (int c = 0; c < 8; ++c) sum += p[c * 4096];
    wbf[g] = sum;
  }
}

// Per-batch: product = t1^T w; S = sigmoid(product+be); E = Ve*S; A = softmax_t(E)
__global__ __launch_bounds__(256) void k3_attn(const float* __restrict__ t1,
    const float* __restrict__ wbuf, const float* __restrict__ be,
    const float* __restrict__ Ve, float* __restrict__ Amat) {
  const int b = blockIdx.x;
  const int tid = threadIdx.x;
  const int lane = tid & 63;
  const int tg = tid >> 6;
  __shared__ float bufA[64 * 65];
  __shared__ float bufB[64 * 65];
  __shared__ float red[2][4][64];
#pragma unroll
  for (int q = 0; q < 16; ++q) {
    const int idx = q * 256 + tid;
    const int r = idx >> 6, c = idx & 63;
    bufA[r * 65 + c] = t1[(size_t)b * 4096 + idx];   // [f][t]
    bufB[r * 65 + c] = wbuf[(size_t)b * 4096 + idx]; // [f][s]
  }
  __syncthreads();
  float prod[16];
#pragma unroll
  for (int j = 0; j < 16; ++j) prod[j] = 0.f;
  for (int f = 0; f < 64; ++f) {
    const float wv = bufB[f * 65 + lane];
#pragma unroll
    for (int j = 0; j < 16; ++j) prod[j] += bufA[f * 65 + tg * 16 + j] * wv;
  }
  __syncthreads();
#pragma unroll
  for (int j = 0; j < 16; ++j) {
    const int tt = tg * 16 + j;
    const float v = prod[j] + be[tt * 64 + lane];
    bufA[tt * 65 + lane] = 1.f / (1.f + __expf(-v));
  }
#pragma unroll
  for (int q = 0; q < 16; ++q) {
    const int idx = q * 256 + tid;
    bufB[(idx >> 6) * 65 + (idx & 63)] = Ve[idx];
  }
  __syncthreads();
  float E[16];
#pragma unroll
  for (int j = 0; j < 16; ++j) E[j] = 0.f;
  for (int s = 0; s < 64; ++s) {
    const float sv = bufA[s * 65 + lane];
#pragma unroll
    for (int j = 0; j < 16; ++j) E[j] += bufB[(tg * 16 + j) * 65 + s] * sv;
  }
  float m = E[0];
#pragma unroll
  for (int j = 1; j < 16; ++j) m = fmaxf(m, E[j]);
  red[0][tg][lane] = m;
  __syncthreads();
  m = fmaxf(fmaxf(red[0][0][lane], red[0][1][lane]),
            fmaxf(red[0][2][lane], red[0][3][lane]));
  float se = 0.f;
  float ex[16];
#pragma unroll
  for (int j = 0; j < 16; ++j) { ex[j] = __expf(E[j] - m); se += ex[j]; }
  red[1][tg][lane] = se;
  __syncthreads();
  const float gs = red[1][0][lane] + red[1][1][lane] + red[1][2][lane] + red[1][3][lane];
  const float inv = 1.f / gs;
#pragma unroll
  for (int j = 0; j < 16; ++j) {
    const int tt = tg * 16 + j;
    Amat[(size_t)b * 4096 + tt * 64 + lane] = ex[j] * inv;
  }
}

// out[b,fn,s] = sum_t x[b,fn,t] * A[b,t,s] via bf16 MFMA. Wave = 16 rows x 64 cols.
__global__ __launch_bounds__(256) void k4_out(const float* __restrict__ x,
    const float* __restrict__ Amat, float* __restrict__ out) {
  const int b = blockIdx.x;
  const int chunk = blockIdx.y;
  const int tid = threadIdx.x;
  const int wv = tid >> 6;
  const int l = tid & 63;
  __shared__ float lA[64 * 65];
  const float* Ab = Amat + (size_t)b * 4096;
#pragma unroll
  for (int q = 0; q < 16; ++q) {
    const int idx = q * 256 + tid;
    lA[(idx >> 6) * 65 + (idx & 63)] = Ab[idx];
  }
  __syncthreads();

  const int krow0 = (l >> 4) * 8;
  const int colb = l & 15;
  bf16x8 Bf[4][2];
#pragma unroll
  for (int nt = 0; nt < 4; ++nt)
#pragma unroll
    for (int kh = 0; kh < 2; ++kh) {
      bf16x8 fr;
#pragma unroll
      for (int j = 0; j < 8; ++j) {
        const int k = kh * 32 + krow0 + j;
        fr[j] = (short)f2bf(lA[k * 65 + nt * 16 + colb]);
      }
      Bf[nt][kh] = fr;
    }

  const float* Xb = x + (size_t)b * (F_ * (size_t)N_ * T_);
  float* Ob = out + (size_t)b * (F_ * (size_t)N_ * T_);
  const int rl = l & 15;
  const int c0 = (l >> 4) * 8;

  for (int it = 0; it < 4; ++it) {
    const int tile = chunk * 16 + wv * 4 + it;  // 0..2047
    const int r = tile * 16 + rl;
    const float* xr = Xb + (size_t)r * T_;
    const float4 v0 = *(const float4*)(xr + c0);
    const float4 v1 = *(const float4*)(xr + c0 + 4);
    const float4 v2 = *(const float4*)(xr + 32 + c0);
    const float4 v3 = *(const float4*)(xr + 32 + c0 + 4);
    bf16x8 a0, a1;
    a0[0] = (short)f2bf(v0.x); a0[1] = (short)f2bf(v0.y);
    a0[2] = (short)f2bf(v0.z); a0[3] = (short)f2bf(v0.w);
    a0[4] = (short)f2bf(v1.x); a0[5] = (short)f2bf(v1.y);
    a0[6] = (short)f2bf(v1.z); a0[7] = (short)f2bf(v1.w);
    a1[0] = (short)f2bf(v2.x); a1[1] = (short)f2bf(v2.y);
    a1[2] = (short)f2bf(v2.z); a1[3] = (short)f2bf(v2.w);
    a1[4] = (short)f2bf(v3.x); a1[5] = (short)f2bf(v3.y);
    a1[6] = (short)f2bf(v3.z); a1[7] = (short)f2bf(v3.w);

    const int rowb = tile * 16 + (l >> 4) * 4;
#pragma unroll
    for (int nt = 0; nt < 4; ++nt) {
      f32x4 c = {0.f, 0.f, 0.f, 0.f};
      c = __builtin_amdgcn_mfma_f32_16x16x32_bf16(a0, Bf[nt][0], c, 0, 0, 0);
      c = __builtin_amdgcn_mfma_f32_16x16x32_bf16(a1, Bf[nt][1], c, 0, 0, 0);
#pragma unroll
      for (int j = 0; j < 4; ++j)
        Ob[(size_t)(rowb + j) * T_ + nt * 16 + colb] = c[j];
    }
  }
}

extern "C" void kernel_launch(void* const* d_in, const int* in_sizes, int n_in,
                              void* d_out, int out_size, void* d_ws, size_t ws_size,
                              hipStream_t stream) {
  const float* x  = (const float*)d_in[0];
  const float* U1 = (const float*)d_in[1];
  const float* U2 = (const float*)d_in[2];
  const float* U3 = (const float*)d_in[3];
  const float* be = (const float*)d_in[4];
  const float* Ve = (const float*)d_in[5];
  float* out = (float*)d_out;
  float* ws = (float*)d_ws;

  float* t1part = ws;                    // 32*32*4096 = 4,194,304 floats (16 MB)
  float* rhs    = t1part + 4194304;      // 32*512*64  = 1,048,576 floats (4 MB)
  float* wpart  = rhs + 1048576;         // 32*8*4096  = 1,048,576 floats (4 MB)
  float* t1     = wpart + 1048576;       // 131072 floats
  float* wbf    = t1 + 131072;           // 131072 floats
  float* Amat   = wbf + 131072;          // 131072 floats

  k1_reduce<<<dim3(32, 32), 256, 0, stream>>>(x, U1, U3, t1part, rhs);
  k2_w<<<dim3(32, 8), 256, 0, stream>>>(rhs, U2, wpart);
  kred<<<1024, 256, 0, stream>>>(t1part, wpart, t1, wbf);
  k3_attn<<<32, 256, 0, stream>>>(t1, wbf, be, Ve, Amat);
  k4_out<<<dim3(32, 128), 256, 0, stream>>>(x, Amat, out);
}

// Round 4
// 191.808 us; speedup vs baseline: 1.3768x; 1.0058x over previous
//
#include <hip/hip_runtime.h>
#include <hip/hip_bf16.h>

#define B_ 32
#define F_ 64
#define N_ 512
#define T_ 64

typedef __attribute__((ext_vector_type(8))) short bf16x8;
typedef __attribute__((ext_vector_type(4))) float f32x4;

__device__ __forceinline__ unsigned short f2bf(float f) {
  union { float f; unsigned int u; } v; v.f = f;
  unsigned int u = v.u;
  unsigned int r = (u + 0x7FFFu + ((u >> 16) & 1u)) >> 16;
  return (unsigned short)r;
}

__device__ __forceinline__ void gl_lds16(const float* g, float* l) {
  __builtin_amdgcn_global_load_lds(
      (const __attribute__((address_space(1))) unsigned int*)(g),
      (__attribute__((address_space(3))) unsigned int*)(l),
      16, 0, 0);
}

// Pass 1 over x. Block=(b, 64-n chunk), 1 block/CU. Wave w owns f in [16w,16w+16).
// 64 slabs of 4KB per wave through a 4-buffer LDS ring, prefetch depth 3,
// counted vmcnt(12).
//   rhs[b,n,t]      = sum_f U3[f]*x[b,f,n,t]   (cross-wave LDS reduce at end)
//   t1part[b,nc,f,t]= sum_{n in 64-chunk} U1[n]*x  (in-reg + shuffle reduce)
__global__ __launch_bounds__(256) void k1_reduce(const float* __restrict__ x,
    const float* __restrict__ U1, const float* __restrict__ U3,
    float* __restrict__ t1part, float* __restrict__ rhs) {
  const int b = blockIdx.x;
  const int nc = blockIdx.y;
  const int n0 = nc * 64;
  const int tid = threadIdx.x;
  const int w = tid >> 6;
  const int lane = tid & 63;
  const int n_sub = lane >> 4;
  const int t0 = (lane & 15) * 4;

  __shared__ float ring[4][4][1024];  // [wave][buf][16n*64t] = 64 KB

  // wave base: x[b, w*16, n0, 0]
  const float* fbase = x + ((size_t)(b * F_ + w * 16) * N_ + n0) * T_;

  float u1c[4][4];
#pragma unroll
  for (int m = 0; m < 4; ++m)
#pragma unroll
    for (int i = 0; i < 4; ++i) u1c[m][i] = U1[n0 + m * 16 + n_sub * 4 + i];

  float racc[4][4][4];  // [m][i][k]
#pragma unroll
  for (int m = 0; m < 4; ++m)
#pragma unroll
    for (int i = 0; i < 4; ++i)
#pragma unroll
      for (int k = 0; k < 4; ++k) racc[m][i][k] = 0.f;

  // prologue: stage slabs 0,1,2 (f=0, m=0..2) into bufs 0,1,2
#pragma unroll
  for (int s0 = 0; s0 < 3; ++s0) {
    const float* s = fbase + s0 * 1024;  // m*16*64
    float* l = &ring[w][s0][0];
#pragma unroll
    for (int c = 0; c < 4; ++c) gl_lds16(s + c * 256 + lane * 4, l + c * 256);
  }

  for (int j = 0; j < 16; ++j) {
    const float u3 = U3[w * 16 + j];
    float p0 = 0.f, p1 = 0.f, p2 = 0.f, p3 = 0.f;
#pragma unroll
    for (int m = 0; m < 4; ++m) {
      // stage slab sidx+3 (sidx = 4j+m) into buf (m+3)&3
      if (j < 15 || m == 0) {
        const int fp = (m == 0) ? j : (j + 1);
        const int mp = (m + 3) & 3;  // (sidx+3)&3
        const float* s = fbase + (size_t)fp * (N_ * T_) + mp * 1024;
        float* l = &ring[w][mp][0];
#pragma unroll
        for (int c = 0; c < 4; ++c) gl_lds16(s + c * 256 + lane * 4, l + c * 256);
      }
      if (j < 15) {
        asm volatile("s_waitcnt vmcnt(12)" ::: "memory");
      } else {
        if (m == 0)      asm volatile("s_waitcnt vmcnt(12)" ::: "memory");
        else if (m == 1) asm volatile("s_waitcnt vmcnt(8)"  ::: "memory");
        else if (m == 2) asm volatile("s_waitcnt vmcnt(4)"  ::: "memory");
        else             asm volatile("s_waitcnt vmcnt(0)"  ::: "memory");
      }
      __builtin_amdgcn_sched_barrier(0);

#pragma unroll
      for (int i = 0; i < 4; ++i) {
        const float4 v = *(const float4*)&ring[w][m][(n_sub * 4 + i) * 64 + t0];
        racc[m][i][0] += u3 * v.x; racc[m][i][1] += u3 * v.y;
        racc[m][i][2] += u3 * v.z; racc[m][i][3] += u3 * v.w;
        p0 += u1c[m][i] * v.x; p1 += u1c[m][i] * v.y;
        p2 += u1c[m][i] * v.z; p3 += u1c[m][i] * v.w;
      }
    }
    // reduce p over the 4 n-subgroups (lane bits 4-5), store t1 partial for this f
    p0 += __shfl_xor(p0, 16); p0 += __shfl_xor(p0, 32);
    p1 += __shfl_xor(p1, 16); p1 += __shfl_xor(p1, 32);
    p2 += __shfl_xor(p2, 16); p2 += __shfl_xor(p2, 32);
    p3 += __shfl_xor(p3, 16); p3 += __shfl_xor(p3, 32);
    if (lane < 16) {
      float4 st; st.x = p0; st.y = p1; st.z = p2; st.w = p3;
      *(float4*)&t1part[((size_t)(b * 8 + nc) * 64 + (w * 16 + j)) * 64 + t0] = st;
    }
  }

  // cross-wave reduce for rhs: wave w dumps its 64n x 64t tile into ring[w]
#pragma unroll
  for (int m = 0; m < 4; ++m)
#pragma unroll
    for (int i = 0; i < 4; ++i) {
      float4 st; st.x = racc[m][i][0]; st.y = racc[m][i][1];
      st.z = racc[m][i][2]; st.w = racc[m][i][3];
      *(float4*)&ring[w][0][(m * 16 + n_sub * 4 + i) * 64 + t0] = st;
    }
  __syncthreads();
  const float* r0 = &ring[0][0][0];
#pragma unroll
  for (int q = 0; q < 16; ++q) {
    const int idx = q * 256 + tid;  // n_local*64 + t, 0..4095
    const float s = r0[idx] + r0[4096 + idx] + r0[8192 + idx] + r0[12288 + idx];
    rhs[((size_t)b * N_ + n0 + (idx >> 6)) * T_ + (idx & 63)] = s;
  }
}

// wpart[b,c,f,s] = sum_{n in 64-chunk c} U2[n,f] * rhs[b,n,s]
__global__ __launch_bounds__(256) void k2_w(const float* __restrict__ rhs,
    const float* __restrict__ U2, float* __restrict__ wpart) {
  const int b = blockIdx.x;
  const int c = blockIdx.y;
  const int n0 = c * 64;
  const int tid = threadIdx.x;
  const int s = tid & 63;
  const int fg = tid >> 6;
  __shared__ float lu2[64 * 64];
  __shared__ float lr[64 * 64];
#pragma unroll
  for (int q = 0; q < 16; ++q) {
    const int idx = q * 256 + tid;
    const int i = idx >> 6, cc = idx & 63;
    lu2[idx] = U2[(size_t)(n0 + i) * F_ + cc];
    lr[idx] = rhs[((size_t)b * N_ + n0 + i) * T_ + cc];
  }
  __syncthreads();
  float acc[16];
#pragma unroll
  for (int j = 0; j < 16; ++j) acc[j] = 0.f;
  for (int i = 0; i < 64; ++i) {
    const float rv = lr[i * 64 + s];
#pragma unroll
    for (int j = 0; j < 16; ++j) acc[j] += lu2[i * 64 + fg * 16 + j] * rv;
  }
#pragma unroll
  for (int j = 0; j < 16; ++j)
    wpart[(size_t)(b * 8 + c) * 4096 + (size_t)(fg * 16 + j) * 64 + s] = acc[j];
}

// Collapse partials: t1[b,f,t] = sum_c t1part ; wbf[b,f,s] = sum_c wpart (both 8-way)
__global__ __launch_bounds__(256) void kred(const float* __restrict__ t1part,
    const float* __restrict__ wpart, float* __restrict__ t1, float* __restrict__ wbf) {
  const int gid = blockIdx.x * 256 + threadIdx.x;
  if (gid < 131072) {
    const int b = gid >> 12, idx = gid & 4095;
    const float* p = t1part + (size_t)b * 8 * 4096 + idx;
    float sum = 0.f;
#pragma unroll
    for (int c = 0; c < 8; ++c) sum += p[c * 4096];
    t1[gid] = sum;
  } else {
    const int g = gid - 131072;
    const int b = g >> 12, idx = g & 4095;
    const float* p = wpart + (size_t)b * 8 * 4096 + idx;
    float sum = 0.f;
#pragma unroll
    for (int c = 0; c < 8; ++c) sum += p[c * 4096];
    wbf[g] = sum;
  }
}

// Per-batch: product = t1^T w; S = sigmoid(product+be); E = Ve*S; A = softmax_t(E)
__global__ __launch_bounds__(256) void k3_attn(const float* __restrict__ t1,
    const float* __restrict__ wbuf, const float* __restrict__ be,
    const float* __restrict__ Ve, float* __restrict__ Amat) {
  const int b = blockIdx.x;
  const int tid = threadIdx.x;
  const int lane = tid & 63;
  const int tg = tid >> 6;
  __shared__ float bufA[64 * 65];
  __shared__ float bufB[64 * 65];
  __shared__ float red[2][4][64];
#pragma unroll
  for (int q = 0; q < 16; ++q) {
    const int idx = q * 256 + tid;
    const int r = idx >> 6, c = idx & 63;
    bufA[r * 65 + c] = t1[(size_t)b * 4096 + idx];   // [f][t]
    bufB[r * 65 + c] = wbuf[(size_t)b * 4096 + idx]; // [f][s]
  }
  __syncthreads();
  float prod[16];
#pragma unroll
  for (int j = 0; j < 16; ++j) prod[j] = 0.f;
  for (int f = 0; f < 64; ++f) {
    const float wv = bufB[f * 65 + lane];
#pragma unroll
    for (int j = 0; j < 16; ++j) prod[j] += bufA[f * 65 + tg * 16 + j] * wv;
  }
  __syncthreads();
#pragma unroll
  for (int j = 0; j < 16; ++j) {
    const int tt = tg * 16 + j;
    const float v = prod[j] + be[tt * 64 + lane];
    bufA[tt * 65 + lane] = 1.f / (1.f + __expf(-v));
  }
#pragma unroll
  for (int q = 0; q < 16; ++q) {
    const int idx = q * 256 + tid;
    bufB[(idx >> 6) * 65 + (idx & 63)] = Ve[idx];
  }
  __syncthreads();
  float E[16];
#pragma unroll
  for (int j = 0; j < 16; ++j) E[j] = 0.f;
  for (int s = 0; s < 64; ++s) {
    const float sv = bufA[s * 65 + lane];
#pragma unroll
    for (int j = 0; j < 16; ++j) E[j] += bufB[(tg * 16 + j) * 65 + s] * sv;
  }
  float m = E[0];
#pragma unroll
  for (int j = 1; j < 16; ++j) m = fmaxf(m, E[j]);
  red[0][tg][lane] = m;
  __syncthreads();
  m = fmaxf(fmaxf(red[0][0][lane], red[0][1][lane]),
            fmaxf(red[0][2][lane], red[0][3][lane]));
  float se = 0.f;
  float ex[16];
#pragma unroll
  for (int j = 0; j < 16; ++j) { ex[j] = __expf(E[j] - m); se += ex[j]; }
  red[1][tg][lane] = se;
  __syncthreads();
  const float gs = red[1][0][lane] + red[1][1][lane] + red[1][2][lane] + red[1][3][lane];
  const float inv = 1.f / gs;
#pragma unroll
  for (int j = 0; j < 16; ++j) {
    const int tt = tg * 16 + j;
    Amat[(size_t)b * 4096 + tt * 64 + lane] = ex[j] * inv;
  }
}

// out[b,fn,s] = sum_t x[b,fn,t] * A[b,t,s] via bf16 MFMA. Wave = 16 rows x 64 cols.
__global__ __launch_bounds__(256) void k4_out(const float* __restrict__ x,
    const float* __restrict__ Amat, float* __restrict__ out) {
  const int b = blockIdx.x;
  const int chunk = blockIdx.y;
  const int tid = threadIdx.x;
  const int wv = tid >> 6;
  const int l = tid & 63;
  __shared__ float lA[64 * 65];
  const float* Ab = Amat + (size_t)b * 4096;
#pragma unroll
  for (int q = 0; q < 16; ++q) {
    const int idx = q * 256 + tid;
    lA[(idx >> 6) * 65 + (idx & 63)] = Ab[idx];
  }
  __syncthreads();

  const int krow0 = (l >> 4) * 8;
  const int colb = l & 15;
  bf16x8 Bf[4][2];
#pragma unroll
  for (int nt = 0; nt < 4; ++nt)
#pragma unroll
    for (int kh = 0; kh < 2; ++kh) {
      bf16x8 fr;
#pragma unroll
      for (int j = 0; j < 8; ++j) {
        const int k = kh * 32 + krow0 + j;
        fr[j] = (short)f2bf(lA[k * 65 + nt * 16 + colb]);
      }
      Bf[nt][kh] = fr;
    }

  const float* Xb = x + (size_t)b * (F_ * (size_t)N_ * T_);
  float* Ob = out + (size_t)b * (F_ * (size_t)N_ * T_);
  const int rl = l & 15;
  const int c0 = (l >> 4) * 8;

  for (int it = 0; it < 4; ++it) {
    const int tile = chunk * 16 + wv * 4 + it;  // 0..2047
    const int r = tile * 16 + rl;
    const float* xr = Xb + (size_t)r * T_;
    const float4 v0 = *(const float4*)(xr + c0);
    const float4 v1 = *(const float4*)(xr + c0 + 4);
    const float4 v2 = *(const float4*)(xr + 32 + c0);
    const float4 v3 = *(const float4*)(xr + 32 + c0 + 4);
    bf16x8 a0, a1;
    a0[0] = (short)f2bf(v0.x); a0[1] = (short)f2bf(v0.y);
    a0[2] = (short)f2bf(v0.z); a0[3] = (short)f2bf(v0.w);
    a0[4] = (short)f2bf(v1.x); a0[5] = (short)f2bf(v1.y);
    a0[6] = (short)f2bf(v1.z); a0[7] = (short)f2bf(v1.w);
    a1[0] = (short)f2bf(v2.x); a1[1] = (short)f2bf(v2.y);
    a1[2] = (short)f2bf(v2.z); a1[3] = (short)f2bf(v2.w);
    a1[4] = (short)f2bf(v3.x); a1[5] = (short)f2bf(v3.y);
    a1[6] = (short)f2bf(v3.z); a1[7] = (short)f2bf(v3.w);

    const int rowb = tile * 16 + (l >> 4) * 4;
#pragma unroll
    for (int nt = 0; nt < 4; ++nt) {
      f32x4 c = {0.f, 0.f, 0.f, 0.f};
      c = __builtin_amdgcn_mfma_f32_16x16x32_bf16(a0, Bf[nt][0], c, 0, 0, 0);
      c = __builtin_amdgcn_mfma_f32_16x16x32_bf16(a1, Bf[nt][1], c, 0, 0, 0);
#pragma unroll
      for (int j = 0; j < 4; ++j)
        Ob[(size_t)(rowb + j) * T_ + nt * 16 + colb] = c[j];
    }
  }
}

extern "C" void kernel_launch(void* const* d_in, const int* in_sizes, int n_in,
                              void* d_out, int out_size, void* d_ws, size_t ws_size,
                              hipStream_t stream) {
  const float* x  = (const float*)d_in[0];
  const float* U1 = (const float*)d_in[1];
  const float* U2 = (const float*)d_in[2];
  const float* U3 = (const float*)d_in[3];
  const float* be = (const float*)d_in[4];
  const float* Ve = (const float*)d_in[5];
  float* out = (float*)d_out;
  float* ws = (float*)d_ws;

  float* t1part = ws;                    // 32*8*4096 = 1,048,576 floats (4 MB)
  float* rhs    = t1part + 1048576;      // 32*512*64 = 1,048,576 floats (4 MB)
  float* wpart  = rhs + 1048576;         // 32*8*4096 = 1,048,576 floats (4 MB)
  float* t1     = wpart + 1048576;       // 131072 floats
  float* wbf    = t1 + 131072;           // 131072 floats
  float* Amat   = wbf + 131072;          // 131072 floats

  k1_reduce<<<dim3(32, 8), 256, 0, stream>>>(x, U1, U3, t1part, rhs);
  k2_w<<<dim3(32, 8), 256, 0, stream>>>(rhs, U2, wpart);
  kred<<<1024, 256, 0, stream>>>(t1part, wpart, t1, wbf);
  k3_attn<<<32, 256, 0, stream>>>(t1, wbf, be, Ve, Amat);
  k4_out<<<dim3(32, 128), 256, 0, stream>>>(x, Amat, out);
}